// Round 5
// baseline (22.293 us; speedup 1.0000x reference)
//
#include <hip/hip_runtime.h>

// NeighborsConvolution: out[z,a,i] = sum_{b,x,j} [|r_b-r_a|<0.5] * (r_b-r_a)_x * W[x,i,j] * feat[z,b,j]
// B=8, N=1024, CIN=COUT=64.
//
// R5 vs R4 (LDS-pipe-bound: ~1350 LDS cycles/wave x 32 waves/CU ~= 18us):
//  - Scan reads geometry via ds_read_b128 supersteps (lane owns 4 candidates):
//    12 b128 reads total vs 48 b32.
//  - Compact writes one b128 {dx,dy,dz,bits(b)} per hit (vs 4 b32).
//  - Process phase reads one b128 per neighbor (vs 4 b32).
//  - Epilogue/process accumulation in f32x2 (v_pk_fma_f32): ~half the VALU.
//  - Scan d2 stays scalar with fp contract(off): bit-exact mask vs numpy.

#define BATCHSZ 8
#define NPTS 1024
#define CIN 64
#define COUT 64
#define NXJ (3 * CIN)   // 192
#define NG (NXJ / 4)    // 48 float4 groups
#define PPB 8           // points (waves) per block
#define BS (PPB * 64)   // 512
#define CAP 128         // per-wave neighbor list capacity (entries)
#define GPW (NG / PPB)  // 6 W-groups per wave in epilogue

typedef float f32x2 __attribute__((ext_vector_type(2)));

// smem layout (floats):
//  [0,3072)     geo (12KB)
//  [3072,7168)  list (8 waves x 128 x float4 = 16KB) / red[8][8][64] after sync
//  [7168,8704)  tmp[8][192] (6KB)
#define SM_LR 3072
#define SM_TMP 7168
#define SM_TOTAL 8704

__global__ __launch_bounds__(256) void transpose_W_kernel(
    const float* __restrict__ W,   // [3][COUT][CIN]
    float* __restrict__ Wt)        // [NG][COUT][4]
{
    const int t = blockIdx.x * 256 + threadIdx.x;
    if (t >= 3 * COUT * CIN) return;
    const int x = t >> 12;
    const int i = (t >> 6) & 63;
    const int j = t & 63;
    const int xj = x * CIN + j;
    Wt[((xj >> 2) * COUT + i) * 4 + (xj & 3)] = W[t];
}

template <bool WT>
__global__ __launch_bounds__(BS, 4) void neigh_conv_kernel(
    const float* __restrict__ feat,  // [B,N,CIN]
    const float* __restrict__ geom,  // [B,N,3]
    const float* __restrict__ Wv,    // WT ? Wt[NG][64][4] : W[3][64][64]
    float* __restrict__ out)         // [B,N,COUT]
{
    const int lane = threadIdx.x & 63;
    const int wv   = threadIdx.x >> 6;
    const int p    = blockIdx.x * PPB + wv;
    const int a    = p & (NPTS - 1);
    const int z    = p >> 10;        // uniform across block (8 | 1024)

    __shared__ __align__(16) float smem[SM_TOTAL];

    // ---- stage geometry (coalesced float4) ----
    {
        const float4* src = (const float4*)(geom + (size_t)z * NPTS * 3);
        float4* dst = (float4*)smem;
        for (int k = threadIdx.x; k < NPTS * 3 / 4; k += BS)
            dst[k] = src[k];
    }
    __syncthreads();

    const float* geo = smem;
    const float gax = geo[a * 3 + 0];
    const float gay = geo[a * 3 + 1];
    const float gaz = geo[a * 3 + 2];
    const float* fz = feat + (size_t)z * NPTS * CIN;

    float4* list4 = (float4*)(smem + SM_LR) + wv * CAP;
    const unsigned long long ltmask = (1ull << lane) - 1ull;

    f32x2 axy = {0.f, 0.f};
    float az2 = 0.f;
    int nn = 0;

    // ---- scan: 4 supersteps x 256 candidates; lane owns candidates 4l..4l+3 ----
    const float4* g4 = (const float4*)geo;
    for (int ss = 0; ss < 4; ++ss) {
        const int fbase = ss * 192 + lane * 3;         // float4 index
        const float4 q0 = g4[fbase + 0];
        const float4 q1 = g4[fbase + 1];
        const float4 q2 = g4[fbase + 2];
        // candidate s coords:
        float cx[4] = {q0.x, q0.w, q1.z, q2.y};
        float cy[4] = {q0.y, q1.x, q1.w, q2.z};
        float cz[4] = {q0.z, q1.y, q2.x, q2.w};
        #pragma unroll
        for (int s = 0; s < 4; ++s) {
            float dx, dy, dz, d2;
            {
                // Bit-exact vs numpy near boundary: no contraction, left-assoc.
                #pragma clang fp contract(off)
                dx = cx[s] - gax;
                dy = cy[s] - gay;
                dz = cz[s] - gaz;
                d2 = dx * dx + dy * dy + dz * dz;
            }
            const bool hit = d2 < 0.25f;
            const unsigned long long m = __ballot(hit);
            const int c = __popcll(m);
            const int b = ss * 256 + 4 * lane + s;
            if (nn + c <= CAP) {            // wave-uniform
                if (hit) {
                    const int slot = nn + __popcll(m & ltmask);
                    float4 e;
                    e.x = dx; e.y = dy; e.z = dz; e.w = __int_as_float(b);
                    list4[slot] = e;
                }
                nn += c;
            } else {
                // overflow fallback (statistically never for this data)
                unsigned long long mm = m;
                while (mm) {
                    const int src = __ffsll(mm) - 1;
                    mm &= mm - 1ull;
                    const float ddx = __shfl(dx, src);
                    const float ddy = __shfl(dy, src);
                    const float ddz = __shfl(dz, src);
                    const int bsrc = ss * 256 + 4 * src + s;
                    const float f = fz[(size_t)bsrc * CIN + lane];
                    axy.x = fmaf(ddx, f, axy.x);
                    axy.y = fmaf(ddy, f, axy.y);
                    az2   = fmaf(ddz, f, az2);
                }
            }
        }
    }

    // pad to multiple of 4 with null records (b=a -> coords 0, contributes 0)
    {
        const int npad = (4 - (nn & 3)) & 3;
        if (lane < npad) {
            float4 e;
            e.x = 0.f; e.y = 0.f; e.z = 0.f; e.w = __int_as_float(a);
            list4[nn + lane] = e;
        }
        nn += npad;
    }

    // ---- process neighbors 4 at a time: b128 list reads + batched feat loads ----
    for (int k = 0; k < nn; k += 4) {
        const float4 e0 = list4[k + 0];
        const float4 e1 = list4[k + 1];
        const float4 e2 = list4[k + 2];
        const float4 e3 = list4[k + 3];
        const float f0 = fz[(size_t)__float_as_int(e0.w) * CIN + lane];
        const float f1 = fz[(size_t)__float_as_int(e1.w) * CIN + lane];
        const float f2 = fz[(size_t)__float_as_int(e2.w) * CIN + lane];
        const float f3 = fz[(size_t)__float_as_int(e3.w) * CIN + lane];
        f32x2 d01; d01.x = e0.x; d01.y = e0.y;
        f32x2 d11; d11.x = e1.x; d11.y = e1.y;
        f32x2 d21; d21.x = e2.x; d21.y = e2.y;
        f32x2 d31; d31.x = e3.x; d31.y = e3.y;
        f32x2 ff0 = {f0, f0}, ff1 = {f1, f1}, ff2 = {f2, f2}, ff3 = {f3, f3};
        axy = d01 * ff0 + axy;  az2 = fmaf(e0.z, f0, az2);
        axy = d11 * ff1 + axy;  az2 = fmaf(e1.z, f1, az2);
        axy = d21 * ff2 + axy;  az2 = fmaf(e2.z, f2, az2);
        axy = d31 * ff3 + axy;  az2 = fmaf(e3.z, f3, az2);
    }

    float* tmp = smem + SM_TMP + wv * NXJ;
    tmp[0 * CIN + lane] = axy.x;
    tmp[1 * CIN + lane] = axy.y;
    tmp[2 * CIN + lane] = az2;
    __syncthreads();   // list region dead after this -> reuse as red

    // ---- epilogue: wave wv owns W groups [6wv,6wv+6), all 8 points ----
    const int g0 = wv * GPW;
    float4 wr[GPW];
    if (WT) {
        const float4* w4 = (const float4*)Wv;
        #pragma unroll
        for (int q = 0; q < GPW; ++q)
            wr[q] = w4[(g0 + q) * COUT + lane];   // coalesced 1KB/instr
    } else {
        #pragma unroll
        for (int q = 0; q < GPW; ++q) {
            const int xj = 4 * (g0 + q);
            wr[q].x = Wv[((xj + 0) >> 6) * 4096 + lane * 64 + ((xj + 0) & 63)];
            wr[q].y = Wv[((xj + 1) >> 6) * 4096 + lane * 64 + ((xj + 1) & 63)];
            wr[q].z = Wv[((xj + 2) >> 6) * 4096 + lane * 64 + ((xj + 2) & 63)];
            wr[q].w = Wv[((xj + 3) >> 6) * 4096 + lane * 64 + ((xj + 3) & 63)];
        }
    }

    float* red = smem + SM_LR;   // red[wv*8+pp][i]
    #pragma unroll
    for (int pp = 0; pp < PPB; ++pp) {
        const float4* t4 = (const float4*)(smem + SM_TMP + pp * NXJ);
        f32x2 facc = {0.f, 0.f};
        #pragma unroll
        for (int q = 0; q < GPW; ++q) {
            const float4 t = t4[g0 + q];          // uniform -> LDS broadcast
            f32x2 ta; ta.x = t.x; ta.y = t.y;
            f32x2 tb; tb.x = t.z; tb.y = t.w;
            f32x2 wa; wa.x = wr[q].x; wa.y = wr[q].y;
            f32x2 wb; wb.x = wr[q].z; wb.y = wr[q].w;
            facc = ta * wa + facc;                // v_pk_fma_f32
            facc = tb * wb + facc;
        }
        red[(wv * PPB + pp) * COUT + lane] = facc.x + facc.y;
    }
    __syncthreads();

    float o = 0.f;
    #pragma unroll
    for (int w = 0; w < PPB; ++w)
        o += red[(w * PPB + wv) * COUT + lane];   // conflict-free

    out[(size_t)p * COUT + lane] = o;
}

extern "C" void kernel_launch(void* const* d_in, const int* in_sizes, int n_in,
                              void* d_out, int out_size, void* d_ws, size_t ws_size,
                              hipStream_t stream) {
    const float* feat = (const float*)d_in[0];  // [8,1024,64]
    const float* geom = (const float*)d_in[1];  // [8,1024,3]
    const float* W    = (const float*)d_in[2];  // [3,64,64]
    float* out        = (float*)d_out;          // [8,1024,64]

    const int nblocks = BATCHSZ * NPTS / PPB;   // 1024 blocks x 512 threads

    if (ws_size >= (size_t)(3 * COUT * CIN) * sizeof(float)) {
        float* Wt = (float*)d_ws;
        transpose_W_kernel<<<(3 * COUT * CIN + 255) / 256, 256, 0, stream>>>(W, Wt);
        neigh_conv_kernel<true><<<nblocks, BS, 0, stream>>>(feat, geom, Wt, out);
    } else {
        neigh_conv_kernel<false><<<nblocks, BS, 0, stream>>>(feat, geom, W, out);
    }
}